// Round 4
// baseline (401.997 us; speedup 1.0000x reference)
//
#include <hip/hip_runtime.h>
#include <hip/hip_bf16.h>

// Problem constants
#define Bn 8
#define Cn 64
#define Hn 128
#define Wn 128
#define On 64
#define K2n 9
#define HWn (Hn * Wn)          // 16384
#define APAD 72                // LDS row stride (bf16) for A-tiles

typedef short bf16x8 __attribute__((ext_vector_type(8)));
typedef float f32x4  __attribute__((ext_vector_type(4)));

__device__ __forceinline__ unsigned int f2bf(float f) {
    unsigned int u = __float_as_uint(f);
    return (u + 0x7FFFu + ((u >> 16) & 1u)) >> 16;   // RNE fp32->bf16
}

// ---------------------------------------------------------------------------
// Pre-kernel: repack weight (O,C,3,3) fp32 -> bf16 in EXACT MFMA B-fragment
// order: wt2[slot][lane][8], slot = (k*2+ks)*4+t, lane = q*16+n,
// element j -> (o = t*16+n, c = ks*32+q*8+j).
// ---------------------------------------------------------------------------
__global__ __launch_bounds__(256) void wrepack_kernel(
        const float* __restrict__ w, unsigned short* __restrict__ wt2) {
    int i = blockIdx.x * 256 + threadIdx.x;      // 9*64*64 = 36864
    if (i >= K2n * On * Cn) return;
    int j    = i & 7;
    int lane = (i >> 3) & 63;
    int slot = i >> 9;                            // 0..71
    int t  = slot & 3;
    int ks = (slot >> 2) & 1;
    int k  = slot >> 3;
    int n  = lane & 15;
    int q  = lane >> 4;
    int o  = t * 16 + n;
    int c  = ks * 32 + q * 8 + j;
    wt2[i] = (unsigned short)f2bf(w[o * (Cn * K2n) + c * K2n + k]);
}

// ---------------------------------------------------------------------------
// Fused deformable conv, wave-autonomous (no __syncthreads in main loop).
// Each wave owns 16 consecutive pixels. Per-wave LDS hand-off ordered by
// s_waitcnt lgkmcnt(0) + compiler memory barriers (see post-mortem: TBAA).
// ---------------------------------------------------------------------------
__global__ __launch_bounds__(256, 4) void dcn_kernel(
        const float* __restrict__ x,
        const unsigned short* __restrict__ wt2,
        const float* __restrict__ w_off,
        const float* __restrict__ b_off,
        float* __restrict__ out) {
    __shared__ unsigned short Al[4 * 16 * APAD];   // 4 wave-private A-tiles, 9216 B

    const int tid = threadIdx.x;
    const int bid = blockIdx.x;
    // XCD swizzle: bid&7 selects image -> per-XCD L2 caches one 4.2MB image
    const int logical = ((bid & 7) << 8) | (bid >> 3);    // 2048 blocks
    const int b   = logical >> 8;
    const int hw0 = (logical & 255) << 6;                 // 64-px row segment

    const int lane = tid & 63;
    const int wv   = tid >> 6;
    const int q  = lane >> 4;          // 0..3  (channel group / row group)
    const int sp = lane & 15;          // 0..15 (sampler pixel within wave)
    const int pix0 = hw0 + wv * 16;    // wave's first pixel (16 px, same row)
    const int h  = pix0 >> 7;
    const int w0 = pix0 & 127;

    const float* xb = x + (size_t)b * (Cn * HWn);

    // ---- phase 0: offset conv, wave-private ------------------------------
    float off[18];
    {
        float xv[16];
        const float* xp = xb + (size_t)(q * 16) * HWn + pix0 + sp;
#pragma unroll
        for (int i = 0; i < 16; i++) xv[i] = xp[(size_t)i * HWn];
#pragma unroll
        for (int o = 0; o < 18; o++) {
            const float4* wo = (const float4*)(w_off + o * Cn + q * 16);
            float a = 0.f;
#pragma unroll
            for (int i4 = 0; i4 < 4; i4++) {
                float4 wq = wo[i4];
                a += xv[i4 * 4 + 0] * wq.x + xv[i4 * 4 + 1] * wq.y
                   + xv[i4 * 4 + 2] * wq.z + xv[i4 * 4 + 3] * wq.w;
            }
            off[o] = a;
        }
#pragma unroll
        for (int o = 0; o < 18; o++) {
            off[o] += __shfl_xor(off[o], 16, 64);
            off[o] += __shfl_xor(off[o], 32, 64);
            off[o] += b_off[o];
        }
    }

    // ---- main: 9 taps, wave-local ordering only --------------------------
    f32x4 acc[4];
#pragma unroll
    for (int t = 0; t < 4; t++) acc[t] = (f32x4){0.f, 0.f, 0.f, 0.f};

    unsigned short* Aw = &Al[wv * 16 * APAD];     // this wave's tile
    const int arow = sp * APAD;
    const int koff = q * 8;

    for (int k = 0; k < K2n; k++) {
        // WAR guard: prior tap's frag ds_reads returned before we overwrite.
        // Per-wave waitcnt only — does NOT couple waves (unlike __syncthreads).
        asm volatile("s_waitcnt lgkmcnt(0)" ::: "memory");

        // bilinear state for (pixel sp, tap k)
        const float offy = off[2 * k];
        const float offx = off[2 * k + 1];
        const int kh = k / 3, kw = k - kh * 3;
        const float py  = (float)(h - 1 + kh) + offy;
        const float pxf = (float)(w0 + sp - 1 + kw) + offx;
        const float y0f = floorf(py), x0f = floorf(pxf);
        const float wy1 = py - y0f, wx1 = pxf - x0f;
        const float wy0 = 1.f - wy1, wx0 = 1.f - wx1;
        const int y0 = (int)y0f, x0i = (int)x0f;
        const int y1 = y0 + 1,  x1 = x0i + 1;
        const bool vy0 = (y0 >= 0) && (y0 < Hn);
        const bool vy1 = (y1 >= 0) && (y1 < Hn);
        const bool vx0 = (x0i >= 0) && (x0i < Wn);
        const bool vx1 = (x1 >= 0) && (x1 < Wn);
        const int yc0 = min(max(y0, 0), Hn - 1), yc1 = min(max(y1, 0), Hn - 1);
        const int xc0 = min(max(x0i, 0), Wn - 1), xc1 = min(max(x1, 0), Wn - 1);
        const float w00 = (vy0 && vx0) ? wy0 * wx0 : 0.f;
        const float w01 = (vy0 && vx1) ? wy0 * wx1 : 0.f;
        const float w10 = (vy1 && vx0) ? wy1 * wx0 : 0.f;
        const float w11 = (vy1 && vx1) ? wy1 * wx1 : 0.f;
        int a00 = (q * 16) * HWn + yc0 * Wn + xc0;
        int a01 = (q * 16) * HWn + yc0 * Wn + xc1;
        int a10 = (q * 16) * HWn + yc1 * Wn + xc0;
        int a11 = (q * 16) * HWn + yc1 * Wn + xc1;

        // gather + bilinear + pack: 16 channels, stored as bf16x8 (same type
        // as the frag reads -> alias-visible to the compiler, no TBAA hole)
#pragma unroll
        for (int hf = 0; hf < 2; hf++) {
            unsigned int pk[4];
#pragma unroll
            for (int i = 0; i < 4; i++) {
                float s0 = w00 * xb[a00] + w01 * xb[a01]
                         + w10 * xb[a10] + w11 * xb[a11];
                a00 += HWn; a01 += HWn; a10 += HWn; a11 += HWn;
                float s1 = w00 * xb[a00] + w01 * xb[a01]
                         + w10 * xb[a10] + w11 * xb[a11];
                a00 += HWn; a01 += HWn; a10 += HWn; a11 += HWn;
                pk[i] = f2bf(s0) | (f2bf(s1) << 16);
            }
            union { uint4 u; bf16x8 v; } un;
            un.u = make_uint4(pk[0], pk[1], pk[2], pk[3]);
            *(bf16x8*)&Aw[sp * APAD + q * 16 + hf * 8] = un.v;
        }

        // RAW guard: commit this wave's A-tile stores before frag reads.
        asm volatile("s_waitcnt lgkmcnt(0)" ::: "memory");

#pragma unroll
        for (int ks = 0; ks < 2; ks++) {
            bf16x8 af = *(const bf16x8*)&Aw[arow + ks * 32 + koff];
#pragma unroll
            for (int t = 0; t < 4; t++) {
                bf16x8 bfr = *(const bf16x8*)(wt2
                        + ((size_t)((k * 2 + ks) * 4 + t)) * 512 + lane * 8);
                acc[t] = __builtin_amdgcn_mfma_f32_16x16x32_bf16(af, bfr, acc[t], 0, 0, 0);
            }
        }
    }

    // ---- epilogue: C/D layout col(=o)=lane&15, row(=px)=(lane>>4)*4+r ----
    const int oc = lane & 15;
    const int rg = lane >> 4;
    float* ob = out + (size_t)b * (On * HWn) + pix0;
#pragma unroll
    for (int t = 0; t < 4; t++) {
        const int o = t * 16 + oc;
#pragma unroll
        for (int r = 0; r < 4; r++) {
            ob[(size_t)o * HWn + rg * 4 + r] = acc[t][r];
        }
    }
}

// ---------------------------------------------------------------------------
extern "C" void kernel_launch(void* const* d_in, const int* in_sizes, int n_in,
                              void* d_out, int out_size, void* d_ws, size_t ws_size,
                              hipStream_t stream) {
    const float* x      = (const float*)d_in[0];   // (8,64,128,128)
    const float* weight = (const float*)d_in[1];   // (64,64,3,3)
    const float* w_off  = (const float*)d_in[2];   // (18,64)
    const float* b_off  = (const float*)d_in[3];   // (18,)
    float* out = (float*)d_out;                    // (8,64,128,128)
    unsigned short* wt2 = (unsigned short*)d_ws;   // bf16 frag-packed, 73728 B

    wrepack_kernel<<<(K2n * On * Cn + 255) / 256, 256, 0, stream>>>(weight, wt2);
    dcn_kernel<<<2048, 256, 0, stream>>>(x, wt2, w_off, b_off, out);
}

// Round 5
// 194.881 us; speedup vs baseline: 2.0628x; 2.0628x over previous
//
#include <hip/hip_runtime.h>

// Problem constants
#define Bn 8
#define Cn 64
#define Hn 128
#define Wn 128
#define On 64
#define K2n 9
#define HWn (Hn * Wn)          // 16384
#define OFFP 20                // floats per pixel in offset buffer (18 + pad -> 80B, 16B aligned)

typedef short bf16x8 __attribute__((ext_vector_type(8)));
typedef float f32x4  __attribute__((ext_vector_type(4)));

__device__ __forceinline__ unsigned f2bf(float f) {
    unsigned u = __float_as_uint(f);
    return (u + 0x7FFFu + ((u >> 16) & 1u)) >> 16;   // RNE fp32->bf16
}
__device__ __forceinline__ float bflo(unsigned u) { return __uint_as_float(u << 16); }
__device__ __forceinline__ float bfhi(unsigned u) { return __uint_as_float(u & 0xFFFF0000u); }

// ---------------------------------------------------------------------------
// wrepack: weight (O,C,3,3) fp32 -> bf16 in exact MFMA B-fragment order:
// wt2[slot][lane][8], slot=(k*2+ks)*4+t, lane=q*16+n, elem j -> (o=t*16+n,
// c=ks*32+q*8+j).  (unchanged from R4 — verified correct)
// ---------------------------------------------------------------------------
__global__ __launch_bounds__(256) void wrepack_kernel(
        const float* __restrict__ w, unsigned short* __restrict__ wt2) {
    int i = blockIdx.x * 256 + threadIdx.x;      // 36864
    if (i >= K2n * On * Cn) return;
    int j    = i & 7;
    int lane = (i >> 3) & 63;
    int slot = i >> 9;
    int t  = slot & 3;
    int ks = (slot >> 2) & 1;
    int k  = slot >> 3;
    int n  = lane & 15;
    int q  = lane >> 4;
    int o  = t * 16 + n;
    int c  = ks * 32 + q * 8 + j;
    wt2[i] = (unsigned short)f2bf(w[o * (Cn * K2n) + c * K2n + k]);
}

// ---------------------------------------------------------------------------
// prep: per 64-pixel tile: stage x (64px x 64ch) in LDS, then
//   (a) write NHWC bf16-pair transpose xT[(b*HW+px)*32 + c/2]
//   (b) offset 1x1 conv: wave wv computes o = 4j+wv (18 channels total),
//       w_off reads are wave-uniform -> scalar loads. off[b][px][20].
// ---------------------------------------------------------------------------
__global__ __launch_bounds__(256) void prep_kernel(
        const float* __restrict__ x,
        const float* __restrict__ w_off,
        const float* __restrict__ b_off,
        unsigned* __restrict__ xT,
        float* __restrict__ offb) {
    __shared__ float tile[64 * 65];              // pad 65 -> conflict-free
    const int t   = threadIdx.x;
    const int bid = blockIdx.x;                  // 2048 = 8 b x 256 tiles
    const int b   = bid >> 8;
    const int px0 = (bid & 255) << 6;

    // stage: coalesced row reads
    {
        const int p = t & 63, wvl = t >> 6;
        const float* xp = x + (size_t)b * (Cn * HWn) + px0 + p;
#pragma unroll
        for (int j = 0; j < 16; j++) {
            const int c = j * 4 + wvl;
            tile[p * 65 + c] = xp[(size_t)c * HWn];
        }
    }
    __syncthreads();

    // NHWC bf16 write: lane c2 = channel pair, coalesced 128B/wave stores
    {
        const int c2 = t & 31, r = t >> 5;       // r in 0..7
        unsigned* dst = xT + ((size_t)b * HWn + px0) * 32;
#pragma unroll
        for (int j = 0; j < 8; j++) {
            const int p = j * 8 + r;
            const unsigned lo = f2bf(tile[p * 65 + c2 * 2]);
            const unsigned hi = f2bf(tile[p * 65 + c2 * 2 + 1]);
            dst[p * 32 + c2] = lo | (hi << 16);
        }
    }

    // offset conv: lane = px, wave wvl owns offset channels o = 4j + wvl
    {
        const int wvl = t >> 6, p = t & 63;
        const int o0 = wvl, o1 = 4 + wvl, o2 = 8 + wvl, o3 = 12 + wvl, o4 = 16 + wvl;
        float a0 = 0.f, a1 = 0.f, a2 = 0.f, a3 = 0.f, a4 = 0.f;
        for (int c = 0; c < Cn; c++) {
            const float xv = tile[p * 65 + c];   // (p+c)&31 banks: 2-way, free
            a0 += xv * w_off[o0 * Cn + c];       // uniform -> s_load
            a1 += xv * w_off[o1 * Cn + c];
            a2 += xv * w_off[o2 * Cn + c];
            a3 += xv * w_off[o3 * Cn + c];
            if (wvl < 2) a4 += xv * w_off[o4 * Cn + c];
        }
        float* op = offb + ((size_t)b * HWn + px0 + p) * OFFP;
        op[o0] = a0 + b_off[o0];
        op[o1] = a1 + b_off[o1];
        op[o2] = a2 + b_off[o2];
        op[o3] = a3 + b_off[o3];
        if (wvl < 2) op[o4] = a4 + b_off[o4];
    }
}

// ---------------------------------------------------------------------------
// Main kernel: zero LDS.  Wave owns 16 px; lane (q,sp): channels
// {ks*32+q*8 .. +8} of pixel sp -> A-frag built entirely in registers from
// NHWC-bf16 corner loads (dwordx4 each).  8 MFMAs per tap.
// ---------------------------------------------------------------------------
__global__ __launch_bounds__(256, 4) void dcn_kernel(
        const unsigned* __restrict__ xT,
        const unsigned short* __restrict__ wt2,
        const float* __restrict__ offb,
        float* __restrict__ out) {
    const int tid = threadIdx.x;
    const int bid = blockIdx.x;
    // XCD swizzle: bid&7 = image -> per-XCD L2 holds one 2.1MB bf16 image
    const int logical = ((bid & 7) << 8) | (bid >> 3);   // 2048 blocks
    const int b   = logical >> 8;
    const int hw0 = (logical & 255) << 6;

    const int lane = tid & 63;
    const int wv   = tid >> 6;
    const int q    = lane >> 4;
    const int sp   = lane & 15;
    const int pix0 = hw0 + wv * 16;
    const int pix  = pix0 + sp;
    const int h = pix >> 7;
    const int w = pix & 127;

    const unsigned* xb = xT + (size_t)b * (HWn * 32);    // uint = 2 channels
    const float* op = offb + (size_t)(b * HWn + pix) * OFFP;

    f32x4 acc[4];
#pragma unroll
    for (int t = 0; t < 4; t++) acc[t] = (f32x4){0.f, 0.f, 0.f, 0.f};

#pragma unroll
    for (int k = 0; k < K2n; k++) {
        const float2 ofp = *(const float2*)(op + 2 * k);   // 8B-aligned
        const float offy = ofp.x, offx = ofp.y;
        const int kh = k / 3, kw = k - kh * 3;
        const float py  = (float)(h - 1 + kh) + offy;
        const float pxf = (float)(w - 1 + kw) + offx;
        const float y0f = floorf(py), x0f = floorf(pxf);
        const float wy1 = py - y0f, wx1 = pxf - x0f;
        const float wy0 = 1.f - wy1, wx0 = 1.f - wx1;
        const int y0 = (int)y0f, x0i = (int)x0f;
        const int y1 = y0 + 1,  x1 = x0i + 1;
        const bool vy0 = (y0 >= 0) && (y0 < Hn);
        const bool vy1 = (y1 >= 0) && (y1 < Hn);
        const bool vx0 = (x0i >= 0) && (x0i < Wn);
        const bool vx1 = (x1 >= 0) && (x1 < Wn);
        const int yc0 = min(max(y0, 0), Hn - 1), yc1 = min(max(y1, 0), Hn - 1);
        const int xc0 = min(max(x0i, 0), Wn - 1), xc1 = min(max(x1, 0), Wn - 1);
        const float w00 = (vy0 && vx0) ? wy0 * wx0 : 0.f;
        const float w01 = (vy0 && vx1) ? wy0 * wx1 : 0.f;
        const float w10 = (vy1 && vx0) ? wy1 * wx0 : 0.f;
        const float w11 = (vy1 && vx1) ? wy1 * wx1 : 0.f;
        // corner bases in uint units (pixel chunk = 32 uints = 64 ch)
        const int c00 = (yc0 * Wn + xc0) * 32, c01 = (yc0 * Wn + xc1) * 32;
        const int c10 = (yc1 * Wn + xc0) * 32, c11 = (yc1 * Wn + xc1) * 32;

#pragma unroll
        for (int ks = 0; ks < 2; ks++) {
            const int ro = ks * 16 + q * 4;       // this lane's 8-ch run
            const uint4 u00 = *(const uint4*)(xb + c00 + ro);
            const uint4 u01 = *(const uint4*)(xb + c01 + ro);
            const uint4 u10 = *(const uint4*)(xb + c10 + ro);
            const uint4 u11 = *(const uint4*)(xb + c11 + ro);

            union { unsigned u[4]; bf16x8 v; } af;
#pragma unroll
            for (int i = 0; i < 4; i++) {
                const unsigned a = (&u00.x)[i], bb = (&u01.x)[i];
                const unsigned c = (&u10.x)[i], d = (&u11.x)[i];
                const float slo = w00 * bflo(a) + w01 * bflo(bb)
                                + w10 * bflo(c) + w11 * bflo(d);
                const float shi = w00 * bfhi(a) + w01 * bfhi(bb)
                                + w10 * bfhi(c) + w11 * bfhi(d);
                af.u[i] = f2bf(slo) | (f2bf(shi) << 16);
            }

            const unsigned short* bp = wt2 + (size_t)((k * 2 + ks) * 4) * 512 + lane * 8;
#pragma unroll
            for (int t = 0; t < 4; t++) {
                bf16x8 bfr = *(const bf16x8*)(bp + t * 512);   // coalesced 1KB
                acc[t] = __builtin_amdgcn_mfma_f32_16x16x32_bf16(af.v, bfr, acc[t], 0, 0, 0);
            }
        }
    }

    // epilogue: C/D layout col(=o)=lane&15, row(=px)=(lane>>4)*4+r  (R4-verified)
    const int oc = lane & 15;
    const int rg = lane >> 4;
    float* ob = out + (size_t)b * (On * HWn) + pix0;
#pragma unroll
    for (int t = 0; t < 4; t++) {
        const int o = t * 16 + oc;
#pragma unroll
        for (int r = 0; r < 4; r++) {
            ob[(size_t)o * HWn + rg * 4 + r] = acc[t][r];
        }
    }
}

// ---------------------------------------------------------------------------
extern "C" void kernel_launch(void* const* d_in, const int* in_sizes, int n_in,
                              void* d_out, int out_size, void* d_ws, size_t ws_size,
                              hipStream_t stream) {
    const float* x      = (const float*)d_in[0];   // (8,64,128,128)
    const float* weight = (const float*)d_in[1];   // (64,64,3,3)
    const float* w_off  = (const float*)d_in[2];   // (18,64)
    const float* b_off  = (const float*)d_in[3];   // (18,)
    float* out = (float*)d_out;                    // (8,64,128,128)

    // workspace layout (27.3 MB total, 16B-aligned sections)
    unsigned*       xT   = (unsigned*)d_ws;                             // 16,777,216 B
    float*          offb = (float*)((char*)d_ws + 16777216);            // 10,485,760 B
    unsigned short* wt2  = (unsigned short*)((char*)d_ws + 27262976);   //     73,728 B

    wrepack_kernel<<<144, 256, 0, stream>>>(weight, wt2);
    prep_kernel<<<2048, 256, 0, stream>>>(x, w_off, b_off, xT, offb);
    dcn_kernel<<<2048, 256, 0, stream>>>(xT, wt2, offb, out);
}

// Round 6
// 169.452 us; speedup vs baseline: 2.3723x; 1.1501x over previous
//
#include <hip/hip_runtime.h>

// Problem constants
#define Bn 8
#define Cn 64
#define Hn 128
#define Wn 128
#define On 64
#define K2n 9
#define HWn (Hn * Wn)          // 16384
#define OLP 20                 // offl row stride (floats): 18 + pad

typedef short bf16x8 __attribute__((ext_vector_type(8)));
typedef float f32x4  __attribute__((ext_vector_type(4)));

__device__ __forceinline__ unsigned f2bf(float f) {
    unsigned u = __float_as_uint(f);
    return (u + 0x7FFFu + ((u >> 16) & 1u)) >> 16;   // RNE fp32->bf16
}
__device__ __forceinline__ float bflo(unsigned u) { return __uint_as_float(u << 16); }
__device__ __forceinline__ float bfhi(unsigned u) { return __uint_as_float(u & 0xFFFF0000u); }

// ---------------------------------------------------------------------------
// wrepack: (a) weight (O,C,3,3) -> bf16 MFMA B-frag order wt2[slot][lane][8],
// slot=(k*2+ks)*4+t, lane=q*16+n, elem j -> (o=t*16+n, c=ks*32+q*8+j).
// (b) w_off (18,64) -> bf16 B-frags woffr[slot][lane][8], slot=ks*2+t,
// o=t*16+n (0 if o>=18), c=ks*32+q*8+j.
// ---------------------------------------------------------------------------
__global__ __launch_bounds__(256) void wrepack_kernel(
        const float* __restrict__ w,
        const float* __restrict__ w_off,
        unsigned short* __restrict__ wt2,
        unsigned short* __restrict__ woffr) {
    int i = blockIdx.x * 256 + threadIdx.x;
    if (i < K2n * On * Cn) {                      // 36864: conv weights
        int j    = i & 7;
        int lane = (i >> 3) & 63;
        int slot = i >> 9;
        int t  = slot & 3;
        int ks = (slot >> 2) & 1;
        int k  = slot >> 3;
        int o  = t * 16 + (lane & 15);
        int c  = ks * 32 + (lane >> 4) * 8 + j;
        wt2[i] = (unsigned short)f2bf(w[o * (Cn * K2n) + c * K2n + k]);
    } else if (i < K2n * On * Cn + 2048) {        // 2048: w_off frags
        int idx  = i - K2n * On * Cn;
        int j    = idx & 7;
        int lane = (idx >> 3) & 63;
        int slot = idx >> 9;                      // 0..3 = ks*2 + t
        int t  = slot & 1;
        int ks = slot >> 1;
        int o  = t * 16 + (lane & 15);
        int c  = ks * 32 + (lane >> 4) * 8 + j;
        woffr[idx] = (o < 18) ? (unsigned short)f2bf(w_off[o * Cn + c]) : 0;
    }
}

// ---------------------------------------------------------------------------
// prep: pure transpose x NCHW fp32 -> xT NHWC bf16-pair (uint = 2 channels).
// ---------------------------------------------------------------------------
__global__ __launch_bounds__(256) void prep_kernel(
        const float* __restrict__ x, unsigned* __restrict__ xT) {
    __shared__ float tile[64 * 65];
    const int t   = threadIdx.x;
    const int bid = blockIdx.x;                  // 2048 = 8 b x 256 tiles
    const int b   = bid >> 8;
    const int px0 = (bid & 255) << 6;

    {   // stage 64px x 64ch, coalesced row reads
        const int p = t & 63, wvl = t >> 6;
        const float* xp = x + (size_t)b * (Cn * HWn) + px0 + p;
#pragma unroll
        for (int j = 0; j < 16; j++) {
            const int c = j * 4 + wvl;
            tile[p * 65 + c] = xp[(size_t)c * HWn];
        }
    }
    __syncthreads();
    {   // pack + coalesced NHWC write
        const int c2 = t & 31, r = t >> 5;
        unsigned* dst = xT + ((size_t)b * HWn + px0) * 32;
#pragma unroll
        for (int j = 0; j < 8; j++) {
            const int p = j * 8 + r;
            const unsigned lo = f2bf(tile[p * 65 + c2 * 2]);
            const unsigned hi = f2bf(tile[p * 65 + c2 * 2 + 1]);
            dst[p * 32 + c2] = lo | (hi << 16);
        }
    }
}

// ---------------------------------------------------------------------------
// Main kernel: wave owns 16 px.  Offset conv = 4 MFMAs (own-pixel A-frags x
// pre-packed w_off B-frags), redistributed via wave-private LDS.  Main loop:
// 9 taps, manual 1-tap lookahead on the 8 corner dwordx4 gathers, A-frag
// built in registers, B-frags from frag-packed global, 8 MFMAs/tap.
// ---------------------------------------------------------------------------
struct Tap { float w00, w01, w10, w11; int c00, c01, c10, c11; };

__device__ __forceinline__ Tap mktap(int k, float offy, float offx, int h, int w) {
    Tap s;
    const int kh = k / 3, kw = k - kh * 3;
    const float py  = (float)(h - 1 + kh) + offy;
    const float pxf = (float)(w - 1 + kw) + offx;
    const float y0f = floorf(py), x0f = floorf(pxf);
    const float wy1 = py - y0f, wx1 = pxf - x0f;
    const float wy0 = 1.f - wy1, wx0 = 1.f - wx1;
    const int y0 = (int)y0f, x0i = (int)x0f;
    const int y1 = y0 + 1,  x1 = x0i + 1;
    const bool vy0 = (y0 >= 0) && (y0 < Hn);
    const bool vy1 = (y1 >= 0) && (y1 < Hn);
    const bool vx0 = (x0i >= 0) && (x0i < Wn);
    const bool vx1 = (x1 >= 0) && (x1 < Wn);
    const int yc0 = min(max(y0, 0), Hn - 1), yc1 = min(max(y1, 0), Hn - 1);
    const int xc0 = min(max(x0i, 0), Wn - 1), xc1 = min(max(x1, 0), Wn - 1);
    s.w00 = (vy0 && vx0) ? wy0 * wx0 : 0.f;
    s.w01 = (vy0 && vx1) ? wy0 * wx1 : 0.f;
    s.w10 = (vy1 && vx0) ? wy1 * wx0 : 0.f;
    s.w11 = (vy1 && vx1) ? wy1 * wx1 : 0.f;
    s.c00 = (yc0 * Wn + xc0) * 32; s.c01 = (yc0 * Wn + xc1) * 32;
    s.c10 = (yc1 * Wn + xc0) * 32; s.c11 = (yc1 * Wn + xc1) * 32;
    return s;
}

__device__ __forceinline__ void loadA(uint4* A, const Tap& s,
                                      const unsigned* __restrict__ xb, int q) {
    const int r0 = q * 4, r1 = 16 + q * 4;
    A[0] = *(const uint4*)(xb + s.c00 + r0);
    A[1] = *(const uint4*)(xb + s.c01 + r0);
    A[2] = *(const uint4*)(xb + s.c10 + r0);
    A[3] = *(const uint4*)(xb + s.c11 + r0);
    A[4] = *(const uint4*)(xb + s.c00 + r1);
    A[5] = *(const uint4*)(xb + s.c01 + r1);
    A[6] = *(const uint4*)(xb + s.c10 + r1);
    A[7] = *(const uint4*)(xb + s.c11 + r1);
}

__device__ __forceinline__ bf16x8 packfrag(const uint4* A, const Tap& s) {
    union { unsigned u[4]; bf16x8 v; } af;
#pragma unroll
    for (int i = 0; i < 4; i++) {
        const unsigned a = (&A[0].x)[i], b = (&A[1].x)[i];
        const unsigned c = (&A[2].x)[i], d = (&A[3].x)[i];
        const float slo = s.w00 * bflo(a) + s.w01 * bflo(b)
                        + s.w10 * bflo(c) + s.w11 * bflo(d);
        const float shi = s.w00 * bfhi(a) + s.w01 * bfhi(b)
                        + s.w10 * bfhi(c) + s.w11 * bfhi(d);
        af.u[i] = f2bf(slo) | (f2bf(shi) << 16);
    }
    return af.v;
}

__global__ __launch_bounds__(256, 3) void dcn_kernel(
        const unsigned* __restrict__ xT,
        const unsigned short* __restrict__ wt2,
        const unsigned short* __restrict__ woffr,
        const float* __restrict__ b_off,
        float* __restrict__ out) {
    __shared__ float offl[4 * 16 * OLP];          // wave-private offsets, 5120 B

    const int tid = threadIdx.x;
    const int bid = blockIdx.x;
    // XCD swizzle: bid&7 = image -> per-XCD L2 holds one 2.1MB bf16 image
    const int logical = ((bid & 7) << 8) | (bid >> 3);   // 2048 blocks
    const int b   = logical >> 8;
    const int hw0 = (logical & 255) << 6;

    const int lane = tid & 63;
    const int wv   = tid >> 6;
    const int q    = lane >> 4;
    const int sp   = lane & 15;
    const int pix0 = hw0 + wv * 16;
    const int pix  = pix0 + sp;
    const int h = pix >> 7;
    const int w = pix & 127;

    const unsigned* xb = xT + (size_t)b * (HWn * 32);    // uint = 2 channels

    // ---- offset conv via MFMA --------------------------------------------
    {
        union { uint4 u; bf16x8 v; } aw0, aw1;
        aw0.u = *(const uint4*)(xb + pix * 32 + q * 4);        // c = q*8..+8
        aw1.u = *(const uint4*)(xb + pix * 32 + 16 + q * 4);   // c = 32+q*8..
        f32x4 oa0 = (f32x4){0.f, 0.f, 0.f, 0.f};
        f32x4 oa1 = (f32x4){0.f, 0.f, 0.f, 0.f};
        const bf16x8 bo00 = *(const bf16x8*)(woffr + 0 * 512 + lane * 8); // ks0,t0
        const bf16x8 bo01 = *(const bf16x8*)(woffr + 1 * 512 + lane * 8); // ks0,t1
        const bf16x8 bo10 = *(const bf16x8*)(woffr + 2 * 512 + lane * 8); // ks1,t0
        const bf16x8 bo11 = *(const bf16x8*)(woffr + 3 * 512 + lane * 8); // ks1,t1
        oa0 = __builtin_amdgcn_mfma_f32_16x16x32_bf16(aw0.v, bo00, oa0, 0, 0, 0);
        oa1 = __builtin_amdgcn_mfma_f32_16x16x32_bf16(aw0.v, bo01, oa1, 0, 0, 0);
        oa0 = __builtin_amdgcn_mfma_f32_16x16x32_bf16(aw1.v, bo10, oa0, 0, 0, 0);
        oa1 = __builtin_amdgcn_mfma_f32_16x16x32_bf16(aw1.v, bo11, oa1, 0, 0, 0);
        // C layout: col=lane&15 = o-part, row=(lane>>4)*4+r = pixel-in-16
        const int oc = lane & 15, rg = lane >> 4;
        float* ol = offl + wv * (16 * OLP);
        const float bo_a = b_off[oc];
#pragma unroll
        for (int r = 0; r < 4; r++)
            ol[(rg * 4 + r) * OLP + oc] = oa0[r] + bo_a;
        if (oc < 2) {
            const float bo_b = b_off[16 + oc];
#pragma unroll
            for (int r = 0; r < 4; r++)
                ol[(rg * 4 + r) * OLP + 16 + oc] = oa1[r] + bo_b;
        }
    }
    // per-wave hand-off: commit LDS writes before cross-lane reads
    asm volatile("s_waitcnt lgkmcnt(0)" ::: "memory");

    const float* ol = offl + wv * (16 * OLP) + sp * OLP;

    // ---- main loop: 9 taps, 1-tap lookahead on A-gathers -----------------
    f32x4 acc[4];
#pragma unroll
    for (int t = 0; t < 4; t++) acc[t] = (f32x4){0.f, 0.f, 0.f, 0.f};

    float2 of0 = *(const float2*)(ol + 0);
    Tap s = mktap(0, of0.x, of0.y, h, w);
    uint4 A[8];
    loadA(A, s, xb, q);

#pragma unroll
    for (int k = 0; k < K2n; k++) {
        Tap sn;
        uint4 An[8];
        if (k < K2n - 1) {
            const float2 ofn = *(const float2*)(ol + 2 * (k + 1));
            sn = mktap(k + 1, ofn.x, ofn.y, h, w);
            loadA(An, sn, xb, q);                 // issued before tap-k consume
        }

        const bf16x8 af0 = packfrag(&A[0], s);    // ks=0 (c 0..31)
        const bf16x8 af1 = packfrag(&A[4], s);    // ks=1 (c 32..63)

        const unsigned short* bp = wt2 + (size_t)(k * 8) * 512 + lane * 8;
#pragma unroll
        for (int t = 0; t < 4; t++) {
            const bf16x8 b0 = *(const bf16x8*)(bp + t * 512);
            acc[t] = __builtin_amdgcn_mfma_f32_16x16x32_bf16(af0, b0, acc[t], 0, 0, 0);
            const bf16x8 b1 = *(const bf16x8*)(bp + (4 + t) * 512);
            acc[t] = __builtin_amdgcn_mfma_f32_16x16x32_bf16(af1, b1, acc[t], 0, 0, 0);
        }

        if (k < K2n - 1) {
            s = sn;
#pragma unroll
            for (int i = 0; i < 8; i++) A[i] = An[i];
        }
    }

    // ---- epilogue: acc[t] = 4 consecutive px -> one dwordx4 per t --------
    const int oc = lane & 15;
    const int rg = lane >> 4;
    float* ob = out + (size_t)b * (On * HWn) + pix0 + rg * 4;
#pragma unroll
    for (int t = 0; t < 4; t++) {
        const int o = t * 16 + oc;
        *(f32x4*)(ob + (size_t)o * HWn) = acc[t];
    }
}

// ---------------------------------------------------------------------------
extern "C" void kernel_launch(void* const* d_in, const int* in_sizes, int n_in,
                              void* d_out, int out_size, void* d_ws, size_t ws_size,
                              hipStream_t stream) {
    const float* x      = (const float*)d_in[0];   // (8,64,128,128)
    const float* weight = (const float*)d_in[1];   // (64,64,3,3)
    const float* w_off  = (const float*)d_in[2];   // (18,64)
    const float* b_off  = (const float*)d_in[3];   // (18,)
    float* out = (float*)d_out;                    // (8,64,128,128)

    // workspace: xT 16 MB | wt2 73728 B | woffr 4096 B
    unsigned*       xT    = (unsigned*)d_ws;
    unsigned short* wt2   = (unsigned short*)((char*)d_ws + 16777216);
    unsigned short* woffr = (unsigned short*)((char*)d_ws + 16777216 + 73728);

    wrepack_kernel<<<152, 256, 0, stream>>>(weight, w_off, wt2, woffr);
    prep_kernel<<<2048, 256, 0, stream>>>(x, xT);
    dcn_kernel<<<2048, 256, 0, stream>>>(xT, wt2, woffr, b_off, out);
}

// Round 8
// 133.428 us; speedup vs baseline: 3.0128x; 1.2700x over previous
//
#include <hip/hip_runtime.h>

// Problem constants
#define Bn 8
#define Cn 64
#define Hn 128
#define Wn 128
#define On 64
#define K2n 9
#define HWn (Hn * Wn)          // 16384
#define OLP 20                 // offl row stride (floats): 18 + pad

typedef short bf16x8 __attribute__((ext_vector_type(8)));
typedef float f32x4  __attribute__((ext_vector_type(4)));

__device__ __forceinline__ unsigned f2bf(float f) {
    unsigned u = __float_as_uint(f);
    return (u + 0x7FFFu + ((u >> 16) & 1u)) >> 16;   // RNE fp32->bf16
}
__device__ __forceinline__ unsigned pkbf(float lo, float hi) {
    return f2bf(lo) | (f2bf(hi) << 16);              // verified form (R6)
}
__device__ __forceinline__ float bflo(unsigned u) { return __uint_as_float(u << 16); }
__device__ __forceinline__ float bfhi(unsigned u) { return __uint_as_float(u & 0xFFFF0000u); }

// ---------------------------------------------------------------------------
// prep: blocks [0,2048): transpose x NCHW fp32 -> xT NHWC bf16-pair.
//       blocks [2048,2200): repack weight + w_off into MFMA B-frag order
//       (wt2[slot][lane][8], slot=(k*2+ks)*4+t, o=t*16+(lane&15),
//        c=ks*32+(lane>>4)*8+j; woffr same with slot=ks*2+t, o>=18 -> 0).
// ---------------------------------------------------------------------------
__global__ __launch_bounds__(256) void prep_kernel(
        const float* __restrict__ x,
        const float* __restrict__ w,
        const float* __restrict__ w_off,
        unsigned* __restrict__ xT,
        unsigned short* __restrict__ wt2,
        unsigned short* __restrict__ woffr) {
    const int tid = threadIdx.x;
    const int bid = blockIdx.x;

    if (bid >= 2048) {                           // ---- weight repack ----
        int i = (bid - 2048) * 256 + tid;        // 38912 = 152*256 exactly
        if (i < K2n * On * Cn) {
            int j    = i & 7;
            int lane = (i >> 3) & 63;
            int slot = i >> 9;
            int t  = slot & 3;
            int ks = (slot >> 2) & 1;
            int k  = slot >> 3;
            int o  = t * 16 + (lane & 15);
            int c  = ks * 32 + (lane >> 4) * 8 + j;
            wt2[i] = (unsigned short)f2bf(w[o * (Cn * K2n) + c * K2n + k]);
        } else {
            int idx  = i - K2n * On * Cn;        // < 2048
            int j    = idx & 7;
            int lane = (idx >> 3) & 63;
            int slot = idx >> 9;                 // 0..3 = ks*2 + t
            int t  = slot & 1;
            int ks = slot >> 1;
            int o  = t * 16 + (lane & 15);
            int c  = ks * 32 + (lane >> 4) * 8 + j;
            woffr[idx] = (o < 18) ? (unsigned short)f2bf(w_off[o * Cn + c]) : 0;
        }
        return;
    }

    // ---- transpose: 64px x 64ch tile ----
    __shared__ float tile[64 * 65];
    const int b   = bid >> 8;
    const int px0 = (bid & 255) << 6;

    {   // float4 reads: thread (c, pq) loads px [pq*16, pq*16+16) of channel c
        const int c = tid >> 2, pq = tid & 3;
        const float4* xp4 = (const float4*)(x + (size_t)b * (Cn * HWn)
                                              + (size_t)c * HWn + px0 + pq * 16);
        float4 v[4];
#pragma unroll
        for (int i = 0; i < 4; i++) v[i] = xp4[i];
#pragma unroll
        for (int i = 0; i < 16; i++)
            tile[(pq * 16 + i) * 65 + c] = (&v[0].x)[i];
    }
    __syncthreads();
    {   // pack + coalesced NHWC write
        const int c2 = tid & 31, r = tid >> 5;
        unsigned* dst = xT + ((size_t)b * HWn + px0) * 32;
#pragma unroll
        for (int j = 0; j < 8; j++) {
            const int p = j * 8 + r;
            dst[p * 32 + c2] = pkbf(tile[p * 65 + c2 * 2], tile[p * 65 + c2 * 2 + 1]);
        }
    }
}

// ---------------------------------------------------------------------------
// Main kernel.  Wave owns 16 px.
// Gather lanes are SP-MAJOR: lane = m*4 + c2 (m = pixel, c2 = 16B chunk), so
// each aligned lane-quad reads contiguous 64B -> TA merges into one request.
// Combined+packed chunks are redistributed to MFMA A-frag lanes via a
// double-buffered wave-private LDS tile (one per-wave lgkmcnt barrier/tap).
// ---------------------------------------------------------------------------
struct Tap { float w00, w01, w10, w11; int c00, c01, c10, c11; };

__device__ __forceinline__ Tap mktap(int k, float offy, float offx, int h, int w) {
    Tap s;
    const int kh = k / 3, kw = k - kh * 3;
    const float py  = (float)(h - 1 + kh) + offy;
    const float pxf = (float)(w - 1 + kw) + offx;
    const float y0f = floorf(py), x0f = floorf(pxf);
    const float wy1 = py - y0f, wx1 = pxf - x0f;
    const float wy0 = 1.f - wy1, wx0 = 1.f - wx1;
    const int y0 = (int)y0f, x0i = (int)x0f;
    const int y1 = y0 + 1,  x1 = x0i + 1;
    const bool vy0 = (y0 >= 0) && (y0 < Hn);
    const bool vy1 = (y1 >= 0) && (y1 < Hn);
    const bool vx0 = (x0i >= 0) && (x0i < Wn);
    const bool vx1 = (x1 >= 0) && (x1 < Wn);
    const int yc0 = min(max(y0, 0), Hn - 1), yc1 = min(max(y1, 0), Hn - 1);
    const int xc0 = min(max(x0i, 0), Wn - 1), xc1 = min(max(x1, 0), Wn - 1);
    s.w00 = (vy0 && vx0) ? wy0 * wx0 : 0.f;
    s.w01 = (vy0 && vx1) ? wy0 * wx1 : 0.f;
    s.w10 = (vy1 && vx0) ? wy1 * wx0 : 0.f;
    s.w11 = (vy1 && vx1) ? wy1 * wx1 : 0.f;
    s.c00 = (yc0 * Wn + xc0) * 32; s.c01 = (yc0 * Wn + xc1) * 32;
    s.c10 = (yc1 * Wn + xc0) * 32; s.c11 = (yc1 * Wn + xc1) * 32;
    return s;
}

__device__ __forceinline__ void combine4(unsigned* dst, const uint4* u, const Tap& s) {
#pragma unroll
    for (int i = 0; i < 4; i++) {
        const unsigned a = (&u[0].x)[i], b = (&u[1].x)[i];
        const unsigned c = (&u[2].x)[i], d = (&u[3].x)[i];
        const float slo = s.w00 * bflo(a) + s.w01 * bflo(b)
                        + s.w10 * bflo(c) + s.w11 * bflo(d);
        const float shi = s.w00 * bfhi(a) + s.w01 * bfhi(b)
                        + s.w10 * bfhi(c) + s.w11 * bfhi(d);
        dst[i] = pkbf(slo, shi);
    }
}

__global__ __launch_bounds__(256, 4) void dcn_kernel(
        const unsigned* __restrict__ xT,
        const unsigned short* __restrict__ wt2,
        const unsigned short* __restrict__ woffr,
        const float* __restrict__ b_off,
        float* __restrict__ out) {
    __shared__ float offl[4 * 16 * OLP];                       // 5120 B
    __shared__ __align__(16) unsigned chunkb[4][2][16 * 36];   // dbuf chunk tiles, 18432 B

    const int tid = threadIdx.x;
    const int bid = blockIdx.x;
    // XCD swizzle: bid&7 = image -> per-XCD L2 holds one 2.1MB bf16 image
    const int logical = ((bid & 7) << 8) | (bid >> 3);         // 2048 blocks
    const int b   = logical >> 8;
    const int hw0 = (logical & 255) << 6;

    const int lane = tid & 63;
    const int wv   = tid >> 6;
    const int q    = lane >> 4;        // consumer: chunk index / K-half group
    const int sp   = lane & 15;        // consumer + prologue pixel
    const int m    = lane >> 2;        // producer pixel (sp-major gather)
    const int c2   = lane & 3;         // producer 16B-chunk within 64B half
    const int pix0 = hw0 + wv * 16;
    const int pix  = pix0 + sp;

    const unsigned* xb = xT + (size_t)b * (HWn * 32);          // uint = 2 channels

    // ---- offset conv via MFMA (R6-verified) ------------------------------
    {
        union { uint4 u; bf16x8 v; } aw0, aw1;
        aw0.u = *(const uint4*)(xb + pix * 32 + q * 4);
        aw1.u = *(const uint4*)(xb + pix * 32 + 16 + q * 4);
        f32x4 oa0 = (f32x4){0.f, 0.f, 0.f, 0.f};
        f32x4 oa1 = (f32x4){0.f, 0.f, 0.f, 0.f};
        const bf16x8 bo00 = *(const bf16x8*)(woffr + 0 * 512 + lane * 8);
        const bf16x8 bo01 = *(const bf16x8*)(woffr + 1 * 512 + lane * 8);
        const bf16x8 bo10 = *(const bf16x8*)(woffr + 2 * 512 + lane * 8);
        const bf16x8 bo11 = *(const bf16x8*)(woffr + 3 * 512 + lane * 8);
        oa0 = __builtin_amdgcn_mfma_f32_16x16x32_bf16(aw0.v, bo00, oa0, 0, 0, 0);
        oa1 = __builtin_amdgcn_mfma_f32_16x16x32_bf16(aw0.v, bo01, oa1, 0, 0, 0);
        oa0 = __builtin_amdgcn_mfma_f32_16x16x32_bf16(aw1.v, bo10, oa0, 0, 0, 0);
        oa1 = __builtin_amdgcn_mfma_f32_16x16x32_bf16(aw1.v, bo11, oa1, 0, 0, 0);
        const int oc = lane & 15, rg = lane >> 4;
        float* ol = offl + wv * (16 * OLP);
        const float bo_a = b_off[oc];
#pragma unroll
        for (int r = 0; r < 4; r++)
            ol[(rg * 4 + r) * OLP + oc] = oa0[r] + bo_a;
        if (oc < 2) {
            const float bo_b = b_off[16 + oc];
#pragma unroll
            for (int r = 0; r < 4; r++)
                ol[(rg * 4 + r) * OLP + 16 + oc] = oa1[r] + bo_b;
        }
    }
    asm volatile("s_waitcnt lgkmcnt(0)" ::: "memory");   // per-wave LDS hand-off

    // producer-side state: this lane samples pixel m
    const float* olp = offl + wv * (16 * OLP) + m * OLP;
    const int pixm = pix0 + m;
    const int hm = pixm >> 7;
    const int wm = pixm & 127;
    unsigned* cwv = &chunkb[wv][0][0];                   // 2 x 576 dwords

    f32x4 acc[4];
#pragma unroll
    for (int t = 0; t < 4; t++) acc[t] = (f32x4){0.f, 0.f, 0.f, 0.f};

#pragma unroll
    for (int k = 0; k < K2n; k++) {
        // ---- produce: gather (TA-mergeable) + bilinear + pack ----
        const float2 of = *(const float2*)(olp + 2 * k);
        const Tap s = mktap(k, of.x, of.y, hm, wm);

        const unsigned* g00 = xb + s.c00 + c2 * 4;
        const unsigned* g01 = xb + s.c01 + c2 * 4;
        const unsigned* g10 = xb + s.c10 + c2 * 4;
        const unsigned* g11 = xb + s.c11 + c2 * 4;
        uint4 u[8];
        u[0] = *(const uint4*)g00;          // half 0: chunk c2   (ks=0)
        u[1] = *(const uint4*)g01;
        u[2] = *(const uint4*)g10;
        u[3] = *(const uint4*)g11;
        u[4] = *(const uint4*)(g00 + 16);   // half 1: chunk 4+c2 (ks=1)
        u[5] = *(const uint4*)(g01 + 16);
        u[6] = *(const uint4*)(g10 + 16);
        u[7] = *(const uint4*)(g11 + 16);

        unsigned A0[4], A1[4];
        combine4(A0, &u[0], s);             // channels c2*8..+8      (ks=0)
        combine4(A1, &u[4], s);             // channels 32+c2*8..+8   (ks=1)

        // ---- redistribute via double-buffered wave-private LDS ----
        unsigned* cb = cwv + (k & 1) * 576;
        *(uint4*)(cb + m * 36 + c2 * 4)      = make_uint4(A0[0], A0[1], A0[2], A0[3]);
        *(uint4*)(cb + m * 36 + 16 + c2 * 4) = make_uint4(A1[0], A1[1], A1[2], A1[3]);

        // RAW: commit writes before frag reads (full compiler barrier too,
        // which pins the uint4-write/bf16x8-read ordering -> no TBAA hole)
        asm volatile("s_waitcnt lgkmcnt(0)" ::: "memory");

        const bf16x8 af0 = *(const bf16x8*)(cb + sp * 36 + q * 4);
        const bf16x8 af1 = *(const bf16x8*)(cb + sp * 36 + 16 + q * 4);

        const unsigned short* bp = wt2 + (size_t)(k * 8) * 512 + lane * 8;
#pragma unroll
        for (int t = 0; t < 4; t++) {
            const bf16x8 b0 = *(const bf16x8*)(bp + t * 512);
            acc[t] = __builtin_amdgcn_mfma_f32_16x16x32_bf16(af0, b0, acc[t], 0, 0, 0);
            const bf16x8 b1 = *(const bf16x8*)(bp + (4 + t) * 512);
            acc[t] = __builtin_amdgcn_mfma_f32_16x16x32_bf16(af1, b1, acc[t], 0, 0, 0);
        }
    }

    // ---- epilogue: C/D layout col(=o)=lane&15, row(=px)=(lane>>4)*4+r ----
    const int oc = lane & 15;
    const int rg = lane >> 4;
    float* ob = out + (size_t)b * (On * HWn) + pix0 + rg * 4;
#pragma unroll
    for (int t = 0; t < 4; t++) {
        const int o = t * 16 + oc;
        *(f32x4*)(ob + (size_t)o * HWn) = acc[t];
    }
}

// ---------------------------------------------------------------------------
extern "C" void kernel_launch(void* const* d_in, const int* in_sizes, int n_in,
                              void* d_out, int out_size, void* d_ws, size_t ws_size,
                              hipStream_t stream) {
    const float* x      = (const float*)d_in[0];   // (8,64,128,128)
    const float* weight = (const float*)d_in[1];   // (64,64,3,3)
    const float* w_off  = (const float*)d_in[2];   // (18,64)
    const float* b_off  = (const float*)d_in[3];   // (18,)
    float* out = (float*)d_out;                    // (8,64,128,128)

    // workspace: xT 16 MB | wt2 73728 B | woffr 4096 B
    unsigned*       xT    = (unsigned*)d_ws;
    unsigned short* wt2   = (unsigned short*)((char*)d_ws + 16777216);
    unsigned short* woffr = (unsigned short*)((char*)d_ws + 16777216 + 73728);

    prep_kernel<<<2200, 256, 0, stream>>>(x, weight, w_off, xT, wt2, woffr);
    dcn_kernel<<<2048, 256, 0, stream>>>(xT, wt2, woffr, b_off, out);
}